// Round 2
// baseline (1097.391 us; speedup 1.0000x reference)
//
#include <hip/hip_runtime.h>
#include <math.h>

// Problem constants
#define B_   64
#define N_   197
#define C_   768
#define H_   12
#define HD_  64
#define BH_  (B_ * H_)          // 768
#define M_   (B_ * N_)          // 12608 rows (divisible by 64: 197*64)
#define SLD  200                // padded row stride for attention matrix

// GEMM tile config (fp32, 4x4 per thread, 256 threads, 64x64 tile)
#define BM 64
#define BN 64
#define BK 16
#define LDA (BM + 4)            // LDS pad: stride 68 floats -> 16B-aligned rows

// Workspace layout (floats) — total must stay under 256 MiB:
//   qkv  : 3 * 9,682,944   @ 0          (Q scaled by 0.125 at write)
//   S    : 768*197*200     @ 29,048,832
//   O    : ALIASES the Q region (exactly 9,682,944 floats; Q dead after k_scores)
// total 59,308,032 floats = 237,232,128 bytes  (< 268,435,456)
#define QKV_ONE   9682944
#define S_OFF     29048832
#define WS_FLOATS 59308032

// ---------------------------------------------------------------------------
// Diagnostic: if workspace is too small, stamp a huge value into out[0] so the
// absmax error is distinguishable from the all-zeros signature (0.691).
__global__ void k_ws_too_small(float* out, float ws_bytes) {
    out[0] = -ws_bytes;
}

// ---------------------------------------------------------------------------
// Kernel 1: qkv = x @ w_qkv^T, scatter into [3][B][H][N][64], scale Q by 1/8
// A [12608][768] row-major, W [2304][768] row-major (both K-contiguous: NT gemm)
__global__ __launch_bounds__(256) void k_qkv(const float* __restrict__ X,
                                             const float* __restrict__ W,
                                             float* __restrict__ qkv) {
    __shared__ float As[BK][LDA];
    __shared__ float Bs[BK][LDA];
    const int tid = threadIdx.x;
    const int m0 = blockIdx.y * BM;     // 0..196 tiles * 64
    const int n0 = blockIdx.x * BN;     // 0..35 tiles * 64
    const int srow = tid >> 2;          // 0..63
    const int sk4  = (tid & 3) << 2;    // 0,4,8,12
    const int ty = tid >> 4, tx = tid & 15;

    const float* Arow = X + (size_t)(m0 + srow) * C_ + sk4;
    const float* Wrow = W + (size_t)(n0 + srow) * C_ + sk4;

    float acc[4][4] = {};
    for (int k0 = 0; k0 < C_; k0 += BK) {
        float4 av = *(const float4*)(Arow + k0);
        float4 bv = *(const float4*)(Wrow + k0);
        __syncthreads();
        As[sk4+0][srow] = av.x; As[sk4+1][srow] = av.y;
        As[sk4+2][srow] = av.z; As[sk4+3][srow] = av.w;
        Bs[sk4+0][srow] = bv.x; Bs[sk4+1][srow] = bv.y;
        Bs[sk4+2][srow] = bv.z; Bs[sk4+3][srow] = bv.w;
        __syncthreads();
        #pragma unroll
        for (int k = 0; k < BK; ++k) {
            float a[4], b[4];
            *(float4*)a = *(const float4*)&As[k][ty << 2];
            *(float4*)b = *(const float4*)&Bs[k][tx << 2];
            #pragma unroll
            for (int i = 0; i < 4; ++i)
                #pragma unroll
                for (int j = 0; j < 4; ++j)
                    acc[i][j] = fmaf(a[i], b[j], acc[i][j]);
        }
    }
    // epilogue: scatter to q/k/v layout, fold softmax scale into Q
    #pragma unroll
    for (int i = 0; i < 4; ++i) {
        const int m = m0 + (ty << 2) + i;
        const int b = m / N_;
        const int n = m - b * N_;
        #pragma unroll
        for (int j = 0; j < 4; ++j) {
            const int d = n0 + (tx << 2) + j;
            const int t3 = d / C_;            // 0=q 1=k 2=v
            const int r  = d - t3 * C_;
            const int h  = r >> 6;
            const int e  = r & 63;
            float v = acc[i][j];
            if (t3 == 0) v *= 0.125f;         // hd^-0.5
            qkv[(size_t)t3 * QKV_ONE + (((size_t)(b * H_ + h)) * N_ + n) * HD_ + e] = v;
        }
    }
}

// ---------------------------------------------------------------------------
// Kernel 2: S[bh] = Q[bh] @ K[bh]^T   (batched NT gemm, M=N=197, K=64)
// S stored [bh][197][SLD]; pad cols 197..199 written as 0 for unguarded PV loads
__global__ __launch_bounds__(256) void k_scores(const float* __restrict__ Q,
                                                const float* __restrict__ K,
                                                float* __restrict__ S) {
    __shared__ float As[BK][LDA];
    __shared__ float Bs[BK][LDA];
    const int tid = threadIdx.x;
    const int bh = blockIdx.z;
    const int m0 = blockIdx.y * BM;
    const int n0 = blockIdx.x * BN;
    const int srow = tid >> 2;
    const int sk4  = (tid & 3) << 2;
    const int ty = tid >> 4, tx = tid & 15;

    const float* Qb = Q + (size_t)bh * N_ * HD_;
    const float* Kb = K + (size_t)bh * N_ * HD_;
    const int am = m0 + srow, bn = n0 + srow;

    float acc[4][4] = {};
    for (int k0 = 0; k0 < HD_; k0 += BK) {
        float4 av = (am < N_) ? *(const float4*)(Qb + (size_t)am * HD_ + k0 + sk4)
                              : make_float4(0.f, 0.f, 0.f, 0.f);
        float4 bv = (bn < N_) ? *(const float4*)(Kb + (size_t)bn * HD_ + k0 + sk4)
                              : make_float4(0.f, 0.f, 0.f, 0.f);
        __syncthreads();
        As[sk4+0][srow] = av.x; As[sk4+1][srow] = av.y;
        As[sk4+2][srow] = av.z; As[sk4+3][srow] = av.w;
        Bs[sk4+0][srow] = bv.x; Bs[sk4+1][srow] = bv.y;
        Bs[sk4+2][srow] = bv.z; Bs[sk4+3][srow] = bv.w;
        __syncthreads();
        #pragma unroll
        for (int k = 0; k < BK; ++k) {
            float a[4], b[4];
            *(float4*)a = *(const float4*)&As[k][ty << 2];
            *(float4*)b = *(const float4*)&Bs[k][tx << 2];
            #pragma unroll
            for (int i = 0; i < 4; ++i)
                #pragma unroll
                for (int j = 0; j < 4; ++j)
                    acc[i][j] = fmaf(a[i], b[j], acc[i][j]);
        }
    }
    float* Sb = S + (size_t)bh * N_ * SLD;
    #pragma unroll
    for (int i = 0; i < 4; ++i) {
        const int m = m0 + (ty << 2) + i;
        if (m >= N_) continue;
        #pragma unroll
        for (int j = 0; j < 4; ++j) {
            const int col = n0 + (tx << 2) + j;
            if (col < N_)        Sb[(size_t)m * SLD + col] = acc[i][j];
            else if (col < SLD)  Sb[(size_t)m * SLD + col] = 0.f;   // zero pad
        }
    }
}

// ---------------------------------------------------------------------------
// Kernel 3: row softmax over the 197 valid cols; one wave per row
__global__ __launch_bounds__(256) void k_softmax(float* __restrict__ S) {
    const int wid = threadIdx.x >> 6, lane = threadIdx.x & 63;
    const int r = blockIdx.x * 4 + wid;          // exact: 151296 rows / 4
    float* row = S + (size_t)r * SLD;
    float x0 = row[lane];
    float x1 = row[64 + lane];
    float x2 = row[128 + lane];                  // 128+63=191 < 197: valid
    float x3 = (lane < 5) ? row[192 + lane] : -1e30f;
    float mx = fmaxf(fmaxf(x0, x1), fmaxf(x2, x3));
    #pragma unroll
    for (int off = 32; off; off >>= 1) mx = fmaxf(mx, __shfl_xor(mx, off));
    float e0 = __expf(x0 - mx), e1 = __expf(x1 - mx), e2 = __expf(x2 - mx);
    float e3 = (lane < 5) ? __expf(x3 - mx) : 0.f;
    float s = e0 + e1 + e2 + e3;
    #pragma unroll
    for (int off = 32; off; off >>= 1) s += __shfl_xor(s, off);
    const float inv = 1.f / s;
    row[lane]       = e0 * inv;
    row[64 + lane]  = e1 * inv;
    row[128 + lane] = e2 * inv;
    if (lane < 5) row[192 + lane] = e3 * inv;
}

// ---------------------------------------------------------------------------
// Kernel 4: global_attn[b][m] = mean_h P[b,h,0,1+m]
__global__ void k_gattn(const float* __restrict__ S, float* __restrict__ out2) {
    const int idx = blockIdx.x * blockDim.x + threadIdx.x;   // exact 12544
    const int b = idx / (N_ - 1), m = idx - b * (N_ - 1);
    float s = 0.f;
    #pragma unroll
    for (int h = 0; h < H_; ++h)
        s += S[((size_t)(b * H_ + h)) * N_ * SLD + 1 + m];
    out2[idx] = s * (1.f / H_);
}

// ---------------------------------------------------------------------------
// Kernel 5: O[bh] = P[bh] @ V[bh]  (NN gemm, M=197, Nout=64, K=197)
// writes O in [B][N][C] layout (head-transposed) for the proj gemm.
// NOTE: O aliases the Q region of the workspace — Q is dead after k_scores,
// and this kernel reads only S and V.
__global__ __launch_bounds__(256) void k_av(const float* __restrict__ S,
                                            const float* __restrict__ V,
                                            float* __restrict__ O) {
    __shared__ float As[BK][LDA];
    __shared__ float Bs[BK][LDA];
    const int tid = threadIdx.x;
    const int bh = blockIdx.y;
    const int m0 = blockIdx.x * BM;
    const int b = bh / H_, h = bh - b * H_;
    const int arow = tid >> 2;
    const int ak4  = (tid & 3) << 2;
    const int bk   = tid >> 4;          // 0..15: k row of V tile
    const int bc4  = (tid & 15) << 2;   // col*4
    const int ty = tid >> 4, tx = tid & 15;

    const float* Sb = S + (size_t)bh * N_ * SLD;
    const float* Vb = V + (size_t)bh * N_ * HD_;

    float acc[4][4] = {};
    for (int k0 = 0; k0 < N_; k0 += BK) {     // 13 steps, last ragged (5)
        const int am = m0 + arow;
        // pad cols 197..199 are zeros; only guard reads that would cross row end
        float4 av = (am < N_ && (k0 + ak4 + 3) < SLD)
                        ? *(const float4*)(Sb + (size_t)am * SLD + k0 + ak4)
                        : make_float4(0.f, 0.f, 0.f, 0.f);
        const int kb = k0 + bk;
        float4 bv = (kb < N_) ? *(const float4*)(Vb + (size_t)kb * HD_ + bc4)
                              : make_float4(0.f, 0.f, 0.f, 0.f);
        __syncthreads();
        As[ak4+0][arow] = av.x; As[ak4+1][arow] = av.y;
        As[ak4+2][arow] = av.z; As[ak4+3][arow] = av.w;
        *(float4*)&Bs[bk][bc4] = bv;
        __syncthreads();
        #pragma unroll
        for (int k = 0; k < BK; ++k) {
            float a[4], bb[4];
            *(float4*)a  = *(const float4*)&As[k][ty << 2];
            *(float4*)bb = *(const float4*)&Bs[k][tx << 2];
            #pragma unroll
            for (int i = 0; i < 4; ++i)
                #pragma unroll
                for (int j = 0; j < 4; ++j)
                    acc[i][j] = fmaf(a[i], bb[j], acc[i][j]);
        }
    }
    #pragma unroll
    for (int i = 0; i < 4; ++i) {
        const int n = m0 + (ty << 2) + i;
        if (n >= N_) continue;
        #pragma unroll
        for (int j = 0; j < 4; ++j) {
            const int e = (tx << 2) + j;
            O[((size_t)b * N_ + n) * C_ + h * HD_ + e] = acc[i][j];
        }
    }
}

// ---------------------------------------------------------------------------
// Kernel 6: out = O @ w_proj^T + b_proj   (NT gemm, M=12608, Nout=768, K=768)
__global__ __launch_bounds__(256) void k_proj(const float* __restrict__ A,
                                              const float* __restrict__ W,
                                              const float* __restrict__ bias,
                                              float* __restrict__ out) {
    __shared__ float As[BK][LDA];
    __shared__ float Bs[BK][LDA];
    const int tid = threadIdx.x;
    const int m0 = blockIdx.y * BM;
    const int n0 = blockIdx.x * BN;
    const int srow = tid >> 2;
    const int sk4  = (tid & 3) << 2;
    const int ty = tid >> 4, tx = tid & 15;

    const float* Arow = A + (size_t)(m0 + srow) * C_ + sk4;
    const float* Wrow = W + (size_t)(n0 + srow) * C_ + sk4;

    float acc[4][4] = {};
    for (int k0 = 0; k0 < C_; k0 += BK) {
        float4 av = *(const float4*)(Arow + k0);
        float4 bv = *(const float4*)(Wrow + k0);
        __syncthreads();
        As[sk4+0][srow] = av.x; As[sk4+1][srow] = av.y;
        As[sk4+2][srow] = av.z; As[sk4+3][srow] = av.w;
        Bs[sk4+0][srow] = bv.x; Bs[sk4+1][srow] = bv.y;
        Bs[sk4+2][srow] = bv.z; Bs[sk4+3][srow] = bv.w;
        __syncthreads();
        #pragma unroll
        for (int k = 0; k < BK; ++k) {
            float a[4], b[4];
            *(float4*)a = *(const float4*)&As[k][ty << 2];
            *(float4*)b = *(const float4*)&Bs[k][tx << 2];
            #pragma unroll
            for (int i = 0; i < 4; ++i)
                #pragma unroll
                for (int j = 0; j < 4; ++j)
                    acc[i][j] = fmaf(a[i], b[j], acc[i][j]);
        }
    }
    #pragma unroll
    for (int i = 0; i < 4; ++i) {
        const int m = m0 + (ty << 2) + i;
        #pragma unroll
        for (int j = 0; j < 4; ++j) {
            const int d = n0 + (tx << 2) + j;
            out[(size_t)m * C_ + d] = acc[i][j] + bias[d];
        }
    }
}

// ---------------------------------------------------------------------------
extern "C" void kernel_launch(void* const* d_in, const int* in_sizes, int n_in,
                              void* d_out, int out_size, void* d_ws, size_t ws_size,
                              hipStream_t stream) {
    const float* x      = (const float*)d_in[0];
    const float* w_qkv  = (const float*)d_in[1];
    const float* w_proj = (const float*)d_in[2];
    const float* b_proj = (const float*)d_in[3];
    float* out = (float*)d_out;
    float* ws  = (float*)d_ws;

    if (ws_size < (size_t)WS_FLOATS * sizeof(float)) {
        // Diagnostic stamp: distinguishable from the all-zeros absmax (0.691)
        k_ws_too_small<<<1, 1, 0, stream>>>(out, (float)ws_size);
        return;
    }

    float* qkv = ws;
    float* Q = qkv;
    float* K = qkv + QKV_ONE;
    float* V = qkv + 2 * (size_t)QKV_ONE;
    float* S = ws + S_OFF;
    float* O = ws;                       // aliases Q (dead after k_scores)

    k_qkv    <<<dim3(36, 197),   256, 0, stream>>>(x, w_qkv, qkv);
    k_scores <<<dim3(4, 4, BH_), 256, 0, stream>>>(Q, K, S);
    k_softmax<<<dim3(37824),     256, 0, stream>>>(S);
    k_gattn  <<<dim3(49),        256, 0, stream>>>(S, out + (size_t)M_ * C_);
    k_av     <<<dim3(4, BH_),    256, 0, stream>>>(S, V, O);
    k_proj   <<<dim3(12, 197),   256, 0, stream>>>(O, w_proj, b_proj, out);
}

// Round 3
// 502.855 us; speedup vs baseline: 2.1823x; 2.1823x over previous
//
#include <hip/hip_runtime.h>
#include <math.h>

// Problem constants
#define B_   64
#define N_   197
#define C_   768
#define H_   12
#define HD_  64
#define BH_  (B_ * H_)          // 768
#define M_   (B_ * N_)          // 12608 rows
#define SLD  200                // padded row stride for attention matrix

// fp32 vector-GEMM tile config (attention path, unchanged from round 2)
#define BM 64
#define BN 64
#define BK 16
#define LDA (BM + 4)

// Workspace layout (floats) — stays under 256 MiB:
//   qkv  : 3 * 9,682,944   @ 0          (Q scaled by 0.125 at write)
//   S    : 768*197*200     @ 29,048,832
//   O    : aliases Q region (Q dead after k_scores)
// total 59,308,032 floats = 237,232,128 bytes
#define QKV_ONE   9682944
#define S_OFF     29048832
#define WS_FLOATS 59308032

typedef _Float16 half8 __attribute__((ext_vector_type(8)));
typedef float    f32x4 __attribute__((ext_vector_type(4)));

// MFMA tile config: 128x128 block tile, BK=32, 256 threads = 4 waves (2x2 of 64x64)
#define MLDS 40   // LDS row stride in halves (80 B): 16B-aligned, conflict-light

// ---------------------------------------------------------------------------
__global__ void k_ws_too_small(float* out, float ws_bytes) { out[0] = -ws_bytes; }

// ---------------------------------------------------------------------------
// Shared MFMA NT-GEMM core: C[128x128 tile] = A[M][K] x B[N][K]^T, fp16 inputs
// converted in-register during staging, fp32 accumulate.
// A-frag: lane holds A[m = lane&15][k = (lane>>4)*8 + j]  (m89 layout)
// B-frag: lane holds B[n = lane&15][k = (lane>>4)*8 + j]  (NT: same pattern)
// C/D:    col = lane&15, row = (lane>>4)*4 + reg
__device__ __forceinline__ void mfma_nt_core(const float* __restrict__ A,
                                             const float* __restrict__ B,
                                             int M, int K, int m0, int n0,
                                             _Float16* As, _Float16* Bs,
                                             f32x4 (&acc)[4][4]) {
    const int tid  = threadIdx.x;
    const int r    = tid >> 1;             // 0..127: staging row
    const int c0   = (tid & 1) << 4;       // 0 or 16 (halves)
    const int wave = tid >> 6, lane = tid & 63;
    const int wr   = (wave >> 1) << 6;     // wave row offset 0/64
    const int wc   = (wave & 1) << 6;      // wave col offset 0/64
    const int ln   = lane & 15, kq = lane >> 4;

    const int  ag   = m0 + r;
    const bool aval = ag < M;              // only last M-tile is ragged
    const float* Ap = A + (size_t)ag * K + c0;
    const float* Bp = B + (size_t)(n0 + r) * K + c0;   // N is multiple of 128

    for (int k0 = 0; k0 < K; k0 += 32) {
        float4 a0, a1, a2, a3;
        if (aval) {
            a0 = *(const float4*)(Ap + k0);      a1 = *(const float4*)(Ap + k0 + 4);
            a2 = *(const float4*)(Ap + k0 + 8);  a3 = *(const float4*)(Ap + k0 + 12);
        } else {
            a0 = a1 = a2 = a3 = make_float4(0.f, 0.f, 0.f, 0.f);
        }
        float4 b0 = *(const float4*)(Bp + k0),     b1 = *(const float4*)(Bp + k0 + 4),
               b2 = *(const float4*)(Bp + k0 + 8), b3 = *(const float4*)(Bp + k0 + 12);

        half8 ha0, ha1, hb0, hb1;
        ha0[0]=(_Float16)a0.x; ha0[1]=(_Float16)a0.y; ha0[2]=(_Float16)a0.z; ha0[3]=(_Float16)a0.w;
        ha0[4]=(_Float16)a1.x; ha0[5]=(_Float16)a1.y; ha0[6]=(_Float16)a1.z; ha0[7]=(_Float16)a1.w;
        ha1[0]=(_Float16)a2.x; ha1[1]=(_Float16)a2.y; ha1[2]=(_Float16)a2.z; ha1[3]=(_Float16)a2.w;
        ha1[4]=(_Float16)a3.x; ha1[5]=(_Float16)a3.y; ha1[6]=(_Float16)a3.z; ha1[7]=(_Float16)a3.w;
        hb0[0]=(_Float16)b0.x; hb0[1]=(_Float16)b0.y; hb0[2]=(_Float16)b0.z; hb0[3]=(_Float16)b0.w;
        hb0[4]=(_Float16)b1.x; hb0[5]=(_Float16)b1.y; hb0[6]=(_Float16)b1.z; hb0[7]=(_Float16)b1.w;
        hb1[0]=(_Float16)b2.x; hb1[1]=(_Float16)b2.y; hb1[2]=(_Float16)b2.z; hb1[3]=(_Float16)b2.w;
        hb1[4]=(_Float16)b3.x; hb1[5]=(_Float16)b3.y; hb1[6]=(_Float16)b3.z; hb1[7]=(_Float16)b3.w;

        __syncthreads();   // protect previous iteration's fragment reads
        *(half8*)&As[r * MLDS + c0]     = ha0;
        *(half8*)&As[r * MLDS + c0 + 8] = ha1;
        *(half8*)&Bs[r * MLDS + c0]     = hb0;
        *(half8*)&Bs[r * MLDS + c0 + 8] = hb1;
        __syncthreads();

        half8 af[4], bf[4];
        #pragma unroll
        for (int t = 0; t < 4; ++t) {
            af[t] = *(const half8*)&As[(wr + t * 16 + ln) * MLDS + kq * 8];
            bf[t] = *(const half8*)&Bs[(wc + t * 16 + ln) * MLDS + kq * 8];
        }
        #pragma unroll
        for (int i = 0; i < 4; ++i)
            #pragma unroll
            for (int j = 0; j < 4; ++j)
                acc[i][j] = __builtin_amdgcn_mfma_f32_16x16x32_f16(af[i], bf[j], acc[i][j], 0, 0, 0);
    }
}

// ---------------------------------------------------------------------------
// Kernel 1: qkv = x @ w_qkv^T via fp16 MFMA; scatter epilogue into
// [3][B][H][N][64] fp32, Q scaled by 0.125.
__global__ __launch_bounds__(256) void k_qkv_mfma(const float* __restrict__ X,
                                                  const float* __restrict__ W,
                                                  float* __restrict__ qkv) {
    __shared__ _Float16 As[128 * MLDS];
    __shared__ _Float16 Bs[128 * MLDS];
    const int m0 = blockIdx.y << 7;
    const int n0 = blockIdx.x << 7;
    f32x4 acc[4][4] = {};
    mfma_nt_core(X, W, M_, C_, m0, n0, As, Bs, acc);

    const int lane = threadIdx.x & 63;
    const int wave = threadIdx.x >> 6;
    const int wr = (wave >> 1) << 6, wc = (wave & 1) << 6;
    const int ln = lane & 15, kq = lane >> 4;
    #pragma unroll
    for (int mt = 0; mt < 4; ++mt) {
        #pragma unroll
        for (int i = 0; i < 4; ++i) {
            const int m = m0 + wr + mt * 16 + kq * 4 + i;
            if (m >= M_) continue;
            const int b = m / N_;
            const int n = m - b * N_;
            #pragma unroll
            for (int nt = 0; nt < 4; ++nt) {
                const int d  = n0 + wc + nt * 16 + ln;
                const int t3 = d / C_;              // 0=q 1=k 2=v
                const int rr = d - t3 * C_;
                const int h  = rr >> 6;
                const int e  = rr & 63;
                float v = acc[mt][nt][i];
                if (t3 == 0) v *= 0.125f;
                qkv[(size_t)t3 * QKV_ONE + (((size_t)(b * H_ + h)) * N_ + n) * HD_ + e] = v;
            }
        }
    }
}

// ---------------------------------------------------------------------------
// Kernel 6: out = O @ w_proj^T + b_proj via fp16 MFMA
__global__ __launch_bounds__(256) void k_proj_mfma(const float* __restrict__ A,
                                                   const float* __restrict__ W,
                                                   const float* __restrict__ bias,
                                                   float* __restrict__ out) {
    __shared__ _Float16 As[128 * MLDS];
    __shared__ _Float16 Bs[128 * MLDS];
    const int m0 = blockIdx.y << 7;
    const int n0 = blockIdx.x << 7;
    f32x4 acc[4][4] = {};
    mfma_nt_core(A, W, M_, C_, m0, n0, As, Bs, acc);

    const int lane = threadIdx.x & 63;
    const int wave = threadIdx.x >> 6;
    const int wr = (wave >> 1) << 6, wc = (wave & 1) << 6;
    const int ln = lane & 15, kq = lane >> 4;
    float bv[4];
    #pragma unroll
    for (int nt = 0; nt < 4; ++nt) bv[nt] = bias[n0 + wc + nt * 16 + ln];
    #pragma unroll
    for (int mt = 0; mt < 4; ++mt) {
        #pragma unroll
        for (int i = 0; i < 4; ++i) {
            const int m = m0 + wr + mt * 16 + kq * 4 + i;
            if (m >= M_) continue;
            #pragma unroll
            for (int nt = 0; nt < 4; ++nt) {
                const int d = n0 + wc + nt * 16 + ln;
                out[(size_t)m * C_ + d] = acc[mt][nt][i] + bv[nt];
            }
        }
    }
}

// ---------------------------------------------------------------------------
// Kernel 2: S[bh] = Q[bh] @ K[bh]^T  (fp32 vector path, unchanged / verified)
__global__ __launch_bounds__(256) void k_scores(const float* __restrict__ Q,
                                                const float* __restrict__ K,
                                                float* __restrict__ S) {
    __shared__ float As[BK][LDA];
    __shared__ float Bs[BK][LDA];
    const int tid = threadIdx.x;
    const int bh = blockIdx.z;
    const int m0 = blockIdx.y * BM;
    const int n0 = blockIdx.x * BN;
    const int srow = tid >> 2;
    const int sk4  = (tid & 3) << 2;
    const int ty = tid >> 4, tx = tid & 15;

    const float* Qb = Q + (size_t)bh * N_ * HD_;
    const float* Kb = K + (size_t)bh * N_ * HD_;
    const int am = m0 + srow, bn = n0 + srow;

    float acc[4][4] = {};
    for (int k0 = 0; k0 < HD_; k0 += BK) {
        float4 av = (am < N_) ? *(const float4*)(Qb + (size_t)am * HD_ + k0 + sk4)
                              : make_float4(0.f, 0.f, 0.f, 0.f);
        float4 bv = (bn < N_) ? *(const float4*)(Kb + (size_t)bn * HD_ + k0 + sk4)
                              : make_float4(0.f, 0.f, 0.f, 0.f);
        __syncthreads();
        As[sk4+0][srow] = av.x; As[sk4+1][srow] = av.y;
        As[sk4+2][srow] = av.z; As[sk4+3][srow] = av.w;
        Bs[sk4+0][srow] = bv.x; Bs[sk4+1][srow] = bv.y;
        Bs[sk4+2][srow] = bv.z; Bs[sk4+3][srow] = bv.w;
        __syncthreads();
        #pragma unroll
        for (int k = 0; k < BK; ++k) {
            float a[4], b[4];
            *(float4*)a = *(const float4*)&As[k][ty << 2];
            *(float4*)b = *(const float4*)&Bs[k][tx << 2];
            #pragma unroll
            for (int i = 0; i < 4; ++i)
                #pragma unroll
                for (int j = 0; j < 4; ++j)
                    acc[i][j] = fmaf(a[i], b[j], acc[i][j]);
        }
    }
    float* Sb = S + (size_t)bh * N_ * SLD;
    #pragma unroll
    for (int i = 0; i < 4; ++i) {
        const int m = m0 + (ty << 2) + i;
        if (m >= N_) continue;
        #pragma unroll
        for (int j = 0; j < 4; ++j) {
            const int col = n0 + (tx << 2) + j;
            if (col < N_)        Sb[(size_t)m * SLD + col] = acc[i][j];
            else if (col < SLD)  Sb[(size_t)m * SLD + col] = 0.f;
        }
    }
}

// ---------------------------------------------------------------------------
// Kernel 3: row softmax (one wave per 197-col row)
__global__ __launch_bounds__(256) void k_softmax(float* __restrict__ S) {
    const int wid = threadIdx.x >> 6, lane = threadIdx.x & 63;
    const int r = blockIdx.x * 4 + wid;
    float* row = S + (size_t)r * SLD;
    float x0 = row[lane];
    float x1 = row[64 + lane];
    float x2 = row[128 + lane];
    float x3 = (lane < 5) ? row[192 + lane] : -1e30f;
    float mx = fmaxf(fmaxf(x0, x1), fmaxf(x2, x3));
    #pragma unroll
    for (int off = 32; off; off >>= 1) mx = fmaxf(mx, __shfl_xor(mx, off));
    float e0 = __expf(x0 - mx), e1 = __expf(x1 - mx), e2 = __expf(x2 - mx);
    float e3 = (lane < 5) ? __expf(x3 - mx) : 0.f;
    float s = e0 + e1 + e2 + e3;
    #pragma unroll
    for (int off = 32; off; off >>= 1) s += __shfl_xor(s, off);
    const float inv = 1.f / s;
    row[lane]       = e0 * inv;
    row[64 + lane]  = e1 * inv;
    row[128 + lane] = e2 * inv;
    if (lane < 5) row[192 + lane] = e3 * inv;
}

// ---------------------------------------------------------------------------
// Kernel 4: global_attn[b][m] = mean_h P[b,h,0,1+m]
__global__ void k_gattn(const float* __restrict__ S, float* __restrict__ out2) {
    const int idx = blockIdx.x * blockDim.x + threadIdx.x;
    const int b = idx / (N_ - 1), m = idx - b * (N_ - 1);
    float s = 0.f;
    #pragma unroll
    for (int h = 0; h < H_; ++h)
        s += S[((size_t)(b * H_ + h)) * N_ * SLD + 1 + m];
    out2[idx] = s * (1.f / H_);
}

// ---------------------------------------------------------------------------
// Kernel 5: O[bh] = P[bh] @ V[bh]  (fp32 vector path, unchanged / verified)
__global__ __launch_bounds__(256) void k_av(const float* __restrict__ S,
                                            const float* __restrict__ V,
                                            float* __restrict__ O) {
    __shared__ float As[BK][LDA];
    __shared__ float Bs[BK][LDA];
    const int tid = threadIdx.x;
    const int bh = blockIdx.y;
    const int m0 = blockIdx.x * BM;
    const int b = bh / H_, h = bh - b * H_;
    const int arow = tid >> 2;
    const int ak4  = (tid & 3) << 2;
    const int bk   = tid >> 4;
    const int bc4  = (tid & 15) << 2;
    const int ty = tid >> 4, tx = tid & 15;

    const float* Sb = S + (size_t)bh * N_ * SLD;
    const float* Vb = V + (size_t)bh * N_ * HD_;

    float acc[4][4] = {};
    for (int k0 = 0; k0 < N_; k0 += BK) {
        const int am = m0 + arow;
        float4 av = (am < N_ && (k0 + ak4 + 3) < SLD)
                        ? *(const float4*)(Sb + (size_t)am * SLD + k0 + ak4)
                        : make_float4(0.f, 0.f, 0.f, 0.f);
        const int kb = k0 + bk;
        float4 bv = (kb < N_) ? *(const float4*)(Vb + (size_t)kb * HD_ + bc4)
                              : make_float4(0.f, 0.f, 0.f, 0.f);
        __syncthreads();
        As[ak4+0][arow] = av.x; As[ak4+1][arow] = av.y;
        As[ak4+2][arow] = av.z; As[ak4+3][arow] = av.w;
        *(float4*)&Bs[bk][bc4] = bv;
        __syncthreads();
        #pragma unroll
        for (int k = 0; k < BK; ++k) {
            float a[4], bb[4];
            *(float4*)a  = *(const float4*)&As[k][ty << 2];
            *(float4*)bb = *(const float4*)&Bs[k][tx << 2];
            #pragma unroll
            for (int i = 0; i < 4; ++i)
                #pragma unroll
                for (int j = 0; j < 4; ++j)
                    acc[i][j] = fmaf(a[i], bb[j], acc[i][j]);
        }
    }
    #pragma unroll
    for (int i = 0; i < 4; ++i) {
        const int n = m0 + (ty << 2) + i;
        if (n >= N_) continue;
        #pragma unroll
        for (int j = 0; j < 4; ++j) {
            const int e = (tx << 2) + j;
            O[((size_t)b * N_ + n) * C_ + h * HD_ + e] = acc[i][j];
        }
    }
}

// ---------------------------------------------------------------------------
extern "C" void kernel_launch(void* const* d_in, const int* in_sizes, int n_in,
                              void* d_out, int out_size, void* d_ws, size_t ws_size,
                              hipStream_t stream) {
    const float* x      = (const float*)d_in[0];
    const float* w_qkv  = (const float*)d_in[1];
    const float* w_proj = (const float*)d_in[2];
    const float* b_proj = (const float*)d_in[3];
    float* out = (float*)d_out;
    float* ws  = (float*)d_ws;

    if (ws_size < (size_t)WS_FLOATS * sizeof(float)) {
        k_ws_too_small<<<1, 1, 0, stream>>>(out, (float)ws_size);
        return;
    }

    float* qkv = ws;
    float* Q = qkv;
    float* K = qkv + QKV_ONE;
    float* V = qkv + 2 * (size_t)QKV_ONE;
    float* S = ws + S_OFF;
    float* O = ws;                       // aliases Q (dead after k_scores)

    k_qkv_mfma <<<dim3(18, 99),   256, 0, stream>>>(x, w_qkv, qkv);
    k_scores   <<<dim3(4, 4, BH_), 256, 0, stream>>>(Q, K, S);
    k_softmax  <<<dim3(37824),     256, 0, stream>>>(S);
    k_gattn    <<<dim3(49),        256, 0, stream>>>(S, out + (size_t)M_ * C_);
    k_av       <<<dim3(4, BH_),    256, 0, stream>>>(S, V, O);
    k_proj_mfma<<<dim3(6, 99),     256, 0, stream>>>(O, w_proj, b_proj, out);
}

// Round 4
// 274.115 us; speedup vs baseline: 4.0034x; 1.8345x over previous
//
#include <hip/hip_runtime.h>
#include <math.h>

// Problem constants
#define B_   64
#define N_   197
#define C_   768
#define H_   12
#define HD_  64
#define BH_  (B_ * H_)          // 768
#define M_   (B_ * N_)          // 12608

typedef _Float16 half8 __attribute__((ext_vector_type(8)));
typedef float    f32x4 __attribute__((ext_vector_type(4)));

// MFMA NT-GEMM tile: 128x128 block, BK=32 halves, 4 waves (2x2 of 64x64)
#define MLDS 40   // LDS row stride (halves): 80 B, 16B-aligned, 2-way-max banks

// Workspace byte offsets (all 16B aligned)
#define XH_OFF   0u           // 12608*768 fp16      = 19,365,888 B
#define WQH_OFF  19365888u    // 2304*768 fp16       =  3,538,944 B
#define WPH_OFF  22904832u    // 768*768 fp16        =  1,179,648 B
#define QH_OFF   24084480u    // [bh][197][64] fp16  = 19,365,888 B
#define KH_OFF   43450368u    // [bh][197][64] fp16
#define VH_OFF   62816256u    // [bh][197][64] fp16
#define OH_OFF   82182144u    // [B][N][C] fp16      = 19,365,888 B
#define P0_OFF   101548032u   // [bh][196] fp32      =    602,112 B
#define WS_BYTES 102150144u

__device__ __forceinline__ half8 h8zero() {
    half8 z;
    #pragma unroll
    for (int i = 0; i < 8; ++i) z[i] = (_Float16)0;
    return z;
}

// ---------------------------------------------------------------------------
__global__ void k_ws_too_small(float* out, float ws_bytes) { out[0] = -ws_bytes; }

// ---------------------------------------------------------------------------
// fp32 -> fp16 bulk convert (n8 = elements/8)
__global__ __launch_bounds__(256) void k_cvt(const float* __restrict__ src,
                                             _Float16* __restrict__ dst, int n8) {
    const int i = blockIdx.x * blockDim.x + threadIdx.x;
    if (i >= n8) return;
    float4 f0 = *(const float4*)(src + (size_t)i * 8);
    float4 f1 = *(const float4*)(src + (size_t)i * 8 + 4);
    half8 h;
    h[0]=(_Float16)f0.x; h[1]=(_Float16)f0.y; h[2]=(_Float16)f0.z; h[3]=(_Float16)f0.w;
    h[4]=(_Float16)f1.x; h[5]=(_Float16)f1.y; h[6]=(_Float16)f1.z; h[7]=(_Float16)f1.w;
    *(half8*)(dst + (size_t)i * 8) = h;
}

// ---------------------------------------------------------------------------
// NT-GEMM core, fp16 inputs, register-prefetched staging.
// A-frag: lane holds A[m=lane&15][k=(lane>>4)*8+j]; C/D: col=lane&15, row=quad*4+reg
__device__ __forceinline__ void mfma_nt_core_h(const _Float16* __restrict__ A,
                                               const _Float16* __restrict__ B,
                                               int M, int K, int m0, int n0,
                                               _Float16* As, _Float16* Bs,
                                               f32x4 (&acc)[4][4]) {
    const int tid  = threadIdx.x;
    const int r    = tid >> 1;             // 0..127 staging row
    const int c0   = (tid & 1) << 4;       // 0 or 16 halves
    const int wave = tid >> 6, lane = tid & 63;
    const int wr   = (wave >> 1) << 6;
    const int wc   = (wave & 1) << 6;
    const int ln   = lane & 15, kq = lane >> 4;

    const int  ag   = m0 + r;
    const bool aval = ag < M;
    const _Float16* Ap = A + (size_t)(aval ? ag : 0) * K + c0;
    const _Float16* Bp = B + (size_t)(n0 + r) * K + c0;

    half8 a0 = *(const half8*)(Ap),     a1 = *(const half8*)(Ap + 8);
    half8 b0 = *(const half8*)(Bp),     b1 = *(const half8*)(Bp + 8);
    if (!aval) { a0 = h8zero(); a1 = h8zero(); }

    for (int k0 = 0; k0 < K; k0 += 32) {
        __syncthreads();                     // prior frag reads done
        *(half8*)&As[r * MLDS + c0]     = a0;
        *(half8*)&As[r * MLDS + c0 + 8] = a1;
        *(half8*)&Bs[r * MLDS + c0]     = b0;
        *(half8*)&Bs[r * MLDS + c0 + 8] = b1;
        __syncthreads();
        if (k0 + 32 < K) {                   // prefetch next chunk, overlap MFMA
            a0 = *(const half8*)(Ap + k0 + 32); a1 = *(const half8*)(Ap + k0 + 40);
            b0 = *(const half8*)(Bp + k0 + 32); b1 = *(const half8*)(Bp + k0 + 40);
            if (!aval) { a0 = h8zero(); a1 = h8zero(); }
        }
        half8 af[4], bf[4];
        #pragma unroll
        for (int t = 0; t < 4; ++t) {
            af[t] = *(const half8*)&As[(wr + t * 16 + ln) * MLDS + kq * 8];
            bf[t] = *(const half8*)&Bs[(wc + t * 16 + ln) * MLDS + kq * 8];
        }
        #pragma unroll
        for (int i = 0; i < 4; ++i)
            #pragma unroll
            for (int j = 0; j < 4; ++j)
                acc[i][j] = __builtin_amdgcn_mfma_f32_16x16x32_f16(af[i], bf[j], acc[i][j], 0, 0, 0);
    }
}

// ---------------------------------------------------------------------------
// qkv = x @ w_qkv^T (fp16 MFMA); scatter epilogue -> Qh(x0.125)/Kh/Vh fp16
__global__ __launch_bounds__(256) void k_qkv_mfma(const _Float16* __restrict__ Xh,
                                                  const _Float16* __restrict__ Wq,
                                                  _Float16* __restrict__ Qh,
                                                  _Float16* __restrict__ Kh,
                                                  _Float16* __restrict__ Vh) {
    __shared__ _Float16 As[128 * MLDS];
    __shared__ _Float16 Bs[128 * MLDS];
    const int m0 = blockIdx.y << 7;
    const int n0 = blockIdx.x << 7;
    f32x4 acc[4][4] = {};
    mfma_nt_core_h(Xh, Wq, M_, C_, m0, n0, As, Bs, acc);

    const int lane = threadIdx.x & 63;
    const int wave = threadIdx.x >> 6;
    const int wr = (wave >> 1) << 6, wc = (wave & 1) << 6;
    const int ln = lane & 15, kq = lane >> 4;
    #pragma unroll
    for (int mt = 0; mt < 4; ++mt) {
        #pragma unroll
        for (int i = 0; i < 4; ++i) {
            const int m = m0 + wr + mt * 16 + kq * 4 + i;
            if (m >= M_) continue;
            const int b = m / N_;
            const int n = m - b * N_;
            #pragma unroll
            for (int nt = 0; nt < 4; ++nt) {
                const int d  = n0 + wc + nt * 16 + ln;
                const int t3 = d / C_;
                const int rr = d - t3 * C_;
                const int h  = rr >> 6;
                const int e  = rr & 63;
                const size_t off = ((size_t)((b * H_ + h) * N_ + n)) * HD_ + e;
                const float v = acc[mt][nt][i];
                if      (t3 == 0) Qh[off] = (_Float16)(v * 0.125f);
                else if (t3 == 1) Kh[off] = (_Float16)v;
                else              Vh[off] = (_Float16)v;
            }
        }
    }
}

// ---------------------------------------------------------------------------
// out = O @ w_proj^T + b_proj (fp16 MFMA, fp32 out)
__global__ __launch_bounds__(256) void k_proj_mfma(const _Float16* __restrict__ Oh,
                                                   const _Float16* __restrict__ Wp,
                                                   const float* __restrict__ bias,
                                                   float* __restrict__ out) {
    __shared__ _Float16 As[128 * MLDS];
    __shared__ _Float16 Bs[128 * MLDS];
    const int m0 = blockIdx.y << 7;
    const int n0 = blockIdx.x << 7;
    f32x4 acc[4][4] = {};
    mfma_nt_core_h(Oh, Wp, M_, C_, m0, n0, As, Bs, acc);

    const int lane = threadIdx.x & 63;
    const int wave = threadIdx.x >> 6;
    const int wr = (wave >> 1) << 6, wc = (wave & 1) << 6;
    const int ln = lane & 15, kq = lane >> 4;
    float bv[4];
    #pragma unroll
    for (int nt = 0; nt < 4; ++nt) bv[nt] = bias[n0 + wc + nt * 16 + ln];
    #pragma unroll
    for (int mt = 0; mt < 4; ++mt) {
        #pragma unroll
        for (int i = 0; i < 4; ++i) {
            const int m = m0 + wr + mt * 16 + kq * 4 + i;
            if (m >= M_) continue;
            #pragma unroll
            for (int nt = 0; nt < 4; ++nt)
                out[(size_t)m * C_ + n0 + wc + nt * 16 + ln] = acc[mt][nt][i] + bv[nt];
        }
    }
}

// ---------------------------------------------------------------------------
// Fused attention: per (row-tile rt of 64, bh): S=QK^T -> softmax -> O=PV.
// LDS: Ks 208x72 (S phase) aliased by Pl 4x16x232 (PV phase); Vt 64x232.
// Total 59,648 B static.
__global__ __launch_bounds__(256) void k_attn(const _Float16* __restrict__ Qh,
                                              const _Float16* __restrict__ Kh,
                                              const _Float16* __restrict__ Vh,
                                              _Float16* __restrict__ Oh,
                                              float* __restrict__ P0) {
    __shared__ _Float16 lds[29824];
    _Float16* Ks = lds;            // 208*72 = 14976 halves
    _Float16* Pl = lds;            // 4*16*232 = 14848 halves (aliases Ks)
    _Float16* Vt = lds + 14976;    // 64*232  = 14848 halves

    const int bh = blockIdx.y, rt = blockIdx.x;
    const int b = bh / H_, h = bh - b * H_;
    const int tid = threadIdx.x, wave = tid >> 6, lane = tid & 63;
    const int ln = lane & 15, kq = lane >> 4;
    const size_t kvb = (size_t)bh * N_ * HD_;

    // stage K rows -> Ks[key*72 + d]; keys 197..207 zeroed
    for (int idx = tid; idx < 208 * 8; idx += 256) {
        const int key = idx >> 3, c = (idx & 7) << 3;
        half8 v = (key < N_) ? *(const half8*)(Kh + kvb + (size_t)key * HD_ + c) : h8zero();
        *(half8*)&Ks[key * 72 + c] = v;
    }
    // stage V transposed -> Vt[d*232 + key]
    for (int idx = tid; idx < 197 * 8; idx += 256) {
        const int key = idx >> 3, c = (idx & 7) << 3;
        half8 v = *(const half8*)(Vh + kvb + (size_t)key * HD_ + c);
        #pragma unroll
        for (int j = 0; j < 8; ++j) Vt[(c + j) * 232 + key] = v[j];
    }
    // zero Vt pad cols 197..223
    for (int idx = tid; idx < 64 * 27; idx += 256) {
        const int d = idx / 27, k = 197 + (idx - d * 27);
        Vt[d * 232 + k] = (_Float16)0;
    }
    // Q fragments direct from global (row m = lane&15 within this wave's strip)
    const int qrow = rt * 64 + wave * 16 + ln;
    const _Float16* Qp = Qh + kvb + (size_t)((qrow < N_) ? qrow : 0) * HD_ + kq * 8;
    half8 qf0 = *(const half8*)Qp;
    half8 qf1 = *(const half8*)(Qp + 32);
    __syncthreads();

    // S = Q K^T over 13 key tiles
    f32x4 acc[13] = {};
    #pragma unroll
    for (int c = 0; c < 13; ++c) {
        const _Float16* kp = &Ks[(c * 16 + ln) * 72 + kq * 8];
        half8 kf0 = *(const half8*)kp;
        half8 kf1 = *(const half8*)(kp + 32);
        acc[c] = __builtin_amdgcn_mfma_f32_16x16x32_f16(qf0, kf0, acc[c], 0, 0, 0);
        acc[c] = __builtin_amdgcn_mfma_f32_16x16x32_f16(qf1, kf1, acc[c], 0, 0, 0);
    }
    // softmax per row (lane holds rows kq*4+r, cols c*16+ln); mask cols>=197
    float inv4[4];
    #pragma unroll
    for (int r = 0; r < 4; ++r) {
        float m = -1e30f;
        #pragma unroll
        for (int c = 0; c < 13; ++c) {
            float x = ((c * 16 + ln) < N_) ? acc[c][r] : -1e30f;
            acc[c][r] = x;
            m = fmaxf(m, x);
        }
        m = fmaxf(m, __shfl_xor(m, 1)); m = fmaxf(m, __shfl_xor(m, 2));
        m = fmaxf(m, __shfl_xor(m, 4)); m = fmaxf(m, __shfl_xor(m, 8));
        float s = 0.f;
        #pragma unroll
        for (int c = 0; c < 13; ++c) { float e = __expf(acc[c][r] - m); acc[c][r] = e; s += e; }
        s += __shfl_xor(s, 1); s += __shfl_xor(s, 2);
        s += __shfl_xor(s, 4); s += __shfl_xor(s, 8);
        inv4[r] = 1.f / s;
    }
    __syncthreads();                  // all waves done reading Ks -> reuse as Pl

    // write P (fp16) into this wave's strip; cols 208..223 zero
    _Float16* Pw = Pl + wave * 16 * 232;
    #pragma unroll
    for (int c = 0; c < 13; ++c) {
        const int col = c * 16 + ln;
        #pragma unroll
        for (int r = 0; r < 4; ++r)
            Pw[(kq * 4 + r) * 232 + col] = (_Float16)(acc[c][r] * inv4[r]);
    }
    #pragma unroll
    for (int r = 0; r < 4; ++r) Pw[(kq * 4 + r) * 232 + 208 + ln] = (_Float16)0;

    // CLS-row probs for global_attn (row 0 = rt0/wave0/quad0/reg0)
    if (rt == 0 && wave == 0 && kq == 0) {
        #pragma unroll
        for (int c = 0; c < 13; ++c) {
            const int col = c * 16 + ln;
            if (col >= 1 && col < N_) P0[(size_t)bh * 196 + col - 1] = acc[c][0] * inv4[0];
        }
    }
    __syncthreads();                  // P visible (cheap safety barrier)

    // O = P V : 7 k-steps of 32 keys (pads are zeros)
    f32x4 o4[4] = {};
    for (int t = 0; t < 7; ++t) {
        half8 pf = *(const half8*)&Pw[ln * 232 + kq * 8 + 32 * t];
        #pragma unroll
        for (int n = 0; n < 4; ++n) {
            half8 vf = *(const half8*)&Vt[(n * 16 + ln) * 232 + kq * 8 + 32 * t];
            o4[n] = __builtin_amdgcn_mfma_f32_16x16x32_f16(pf, vf, o4[n], 0, 0, 0);
        }
    }
    // store O fp16 [B][N][C]
    const int g0 = rt * 64 + wave * 16 + kq * 4;
    #pragma unroll
    for (int r = 0; r < 4; ++r) {
        const int g = g0 + r;
        if (g >= N_) continue;
        _Float16* op = Oh + ((size_t)b * N_ + g) * C_ + h * HD_;
        #pragma unroll
        for (int n = 0; n < 4; ++n) op[n * 16 + ln] = (_Float16)o4[n][r];
    }
}

// ---------------------------------------------------------------------------
// global_attn[b][m] = mean_h P0[b*12+h][m]
__global__ void k_gattn(const float* __restrict__ P0, float* __restrict__ out2) {
    const int idx = blockIdx.x * blockDim.x + threadIdx.x;   // 12544 exact
    const int b = idx / (N_ - 1), m = idx - b * (N_ - 1);
    float s = 0.f;
    #pragma unroll
    for (int h = 0; h < H_; ++h) s += P0[((size_t)(b * H_ + h)) * 196 + m];
    out2[idx] = s * (1.f / H_);
}

// ---------------------------------------------------------------------------
extern "C" void kernel_launch(void* const* d_in, const int* in_sizes, int n_in,
                              void* d_out, int out_size, void* d_ws, size_t ws_size,
                              hipStream_t stream) {
    const float* x      = (const float*)d_in[0];
    const float* w_qkv  = (const float*)d_in[1];
    const float* w_proj = (const float*)d_in[2];
    const float* b_proj = (const float*)d_in[3];
    float* out = (float*)d_out;
    char* ws   = (char*)d_ws;

    if (ws_size < (size_t)WS_BYTES) {
        k_ws_too_small<<<1, 1, 0, stream>>>(out, (float)ws_size);
        return;
    }

    _Float16* Xh  = (_Float16*)(ws + XH_OFF);
    _Float16* Wqh = (_Float16*)(ws + WQH_OFF);
    _Float16* Wph = (_Float16*)(ws + WPH_OFF);
    _Float16* Qh  = (_Float16*)(ws + QH_OFF);
    _Float16* Kh  = (_Float16*)(ws + KH_OFF);
    _Float16* Vh  = (_Float16*)(ws + VH_OFF);
    _Float16* Oh  = (_Float16*)(ws + OH_OFF);
    float*    P0  = (float*)   (ws + P0_OFF);

    k_cvt<<<4728, 256, 0, stream>>>(x,      Xh,  1210368);   // 12608*768/8
    k_cvt<<< 864, 256, 0, stream>>>(w_qkv,  Wqh, 221184);    // 2304*768/8
    k_cvt<<< 288, 256, 0, stream>>>(w_proj, Wph, 73728);     // 768*768/8

    k_qkv_mfma <<<dim3(18, 99), 256, 0, stream>>>(Xh, Wqh, Qh, Kh, Vh);
    k_attn     <<<dim3(4, BH_), 256, 0, stream>>>(Qh, Kh, Vh, Oh, P0);
    k_gattn    <<<dim3(49),     256, 0, stream>>>(P0, out + (size_t)M_ * C_);
    k_proj_mfma<<<dim3(6, 99),  256, 0, stream>>>(Oh, Wph, b_proj, out);
}